// Round 17
// baseline (122.489 us; speedup 1.0000x reference)
//
#include <hip/hip_runtime.h>
#include <math.h>

typedef _Float16 h2_t __attribute__((ext_vector_type(2)));
typedef _Float16 h4_t __attribute__((ext_vector_type(4)));
typedef _Float16 h8_t __attribute__((ext_vector_type(8)));

#define NP 32
#define KC 31
#define HH 512
#define WW 512
#define BB 4
#define CC 3

#define TXO 64        // 64-wide tile
#define TYO 16        // 16 output rows -> 256-thread block (measured optimum)
#define NT 256        // threads per block
#define TROWS 46      // 16 outputs + 15 + 15 halo
#define TWORDS 48     // row stride in h2 words (4ty x 16tx quarter-wave covers
                      // all 32 banks exactly once -> conflict-free b64)
#define TILEW (TROWS * TWORDS)   // 2208 h2 words, ONE channel at a time
#define WSTR 36       // weight table plane stride in h2 words

// BASE = R12/R16 (session best: 69.8us kernel, 121.3us bench, vs 136.3
// baseline; reproduced twice).
// THIS ROUND (single variable): __launch_bounds__(256,2) -> (256).
// LEDGER EVIDENCE the ",2" was an occupancy CAP, not just an allocator
// floor: measured occupancy tracks the 2nd arg across all 16 rounds --
// (512,2)/(256,2)/(128,2) all pinned ~16-20% (~6-8 waves/CU cap) regardless
// of VGPR(100-128)/LDS(8-65KB)/block size, while the single (256,4) round
// (R7) read 43% (~14 waves). R7 also proved asking for 4 waves/EU forces
// VGPR cap 64 -> 158MB spill -- so the fix is to DROP the clause, not
// raise it. VGPR should stay ~116 -> hardware residency = min(4 waves/SIMD
// by VGPR, 11 blocks by LDS, 4 blocks by grid) = ~16 waves/CU.
// If null, counters will be identical to R16 and this IS the final kernel.
// CLOSED LEVERS (measured): scheduling (R9=R11; R10 DS-pinning poison),
// VALU count (R6 null), LDS capacity (R12 null), barriers (R5), block size
// (512:85 / 256:68 / 128:98us), reg-live staging across dy-loop (R1/R2/R3
// spills), gll staging (R3: loses L2 halo reuse).

__device__ __forceinline__ double plane_of(int i) {
    const double stepd = 50.0 / 31.0;
    return (i < 31) ? (double)i * stepd : 50.0;
}

__device__ __forceinline__ h2_t mkh2(_Float16 a, _Float16 b) {
    h2_t r; r.x = a; r.y = b; return r;
}

__launch_bounds__(256)
__global__ void defocus_kernel(const float* __restrict__ img,
                               const float* __restrict__ coc,
                               float* __restrict__ out) {
    const int tx = threadIdx.x;            // 0..15
    const int ty = threadIdx.y;            // 0..15
    const int tid = ty * 16 + tx;
    const int tilex = blockIdx.x * TXO;
    const int tiley = blockIdx.y * TYO;
    const int b = blockIdx.z;

    __shared__ __align__(16) h2_t wtab[NP * WSTR];   // 4608 B
    __shared__ __align__(16) h2_t tile[TILEW];       // 4416 B  (total ~9.0 KB)

    const int yo = tiley + ty;
    const int xo = tilex + tx * 4;

    // ---- (1) coc load first; its latency hides under the wtab build
    const float4 cv = *(const float4*)&coc[((size_t)b * HH + yo) * WW + xo];

    // ---- (2) in-block wtab build (bit-identical values; 4 passes x 8 planes).
    {
        const int t = tid & 31;               // padded tap position 0..31
        #pragma unroll
        for (int pass = 0; pass < 4; ++pass) {
            const int p = (tid >> 5) + 8 * pass;    // plane 0..31
            const double stepd = 50.0 / 31.0;
            double cocp = (p < 31) ? (double)p * stepd : 50.0;  // numpy linspace
            float gt;
            if (cocp < 0.5) {
                gt = (t == 15) ? 1.f : 0.f;   // identity plane (plane 0 only)
            } else {
                double sigma = cocp / 2.355;
                int k = (int)(2.0 * cocp + 1.0);   // trunc, matches python int()
                if ((k & 1) == 0) k += 1;
                if (k > KC) k = KC;
                int h = k / 2;
                int d = t - 15;
                float denom = (float)(2.0 * sigma * sigma);
                float v = (d >= -h && d <= h && t < KC) ? expf(-(float)(d * d) / denom) : 0.f;
                float s = v;
                #pragma unroll
                for (int off = 1; off < 32; off <<= 1) s += __shfl_xor(s, off, 32);
                gt = v / s;
            }
            const int m = t & 15;
            const int s0 = (t < 16) ? (2 * m) : ((2 * m - 1 < 0) ? 0 : 2 * m - 1);
            const int s1 = (t < 16) ? (2 * m + 1) : (2 * m);
            float w0 = __shfl(gt, s0, 32);
            float w1 = __shfl(gt, s1, 32);
            if (t >= 16 && (2 * m - 1) < 0) w0 = 0.f;   // g[-1] = 0
            h2_t w; w.x = (_Float16)w0; w.y = (_Float16)w1;
            wtab[p * WSTR + t] = w;
            if (t < WSTR - 32) {
                h2_t z; z.x = (_Float16)0.f; z.y = (_Float16)0.f;
                wtab[p * WSTR + 32 + t] = z;
            }
        }
    }

    // ---- (3) per-pixel bin index, exact double-precision boundary semantics
    const float cocf[4] = {cv.x, cv.y, cv.z, cv.w};
    int idx[4];
    #pragma unroll
    for (int j = 0; j < 4; ++j) {
        const double stepd = 50.0 / 31.0;
        double cd = (double)cocf[j];
        int i0 = (int)floor(cd / stepd + 0.5);
        i0 = min(max(i0, 0), 31);
        if (i0 > 0 && cd <= 0.5 * (plane_of(i0 - 1) + plane_of(i0))) {
            i0 -= 1;
        } else if (i0 < 31 && cd > 0.5 * (plane_of(i0) + plane_of(i0 + 1))) {
            i0 += 1;
        }
        idx[j] = i0;
    }

    // Fence: forbid hoisting staging loads up across the f64 region (R1 spill).
    __builtin_amdgcn_sched_barrier(0);

    // ---- (4) stage channel 0
    {
        const float* src = img + (size_t)(b * CC) * HH * WW;
        for (int f = tid; f < TILEW; f += NT) {
            int r = f / TWORDS;
            int w = f - r * TWORDS;
            int gy = tiley - 15 + r;
            int gx = tilex - 15 + 2 * w;
            float v0 = 0.f, v1 = 0.f;
            if ((unsigned)gy < (unsigned)HH) {
                if ((unsigned)gx < (unsigned)WW) v0 = src[gy * WW + gx];
                if ((unsigned)(gx + 1) < (unsigned)WW) v1 = src[gy * WW + gx + 1];
            }
            h2_t pv; pv.x = (_Float16)v0; pv.y = (_Float16)v1;
            tile[f] = pv;
        }
    }

    __syncthreads();   // wtab + tile(ch0) staged

    // ---- (5) gather this thread's 4 weight rows into registers
    // even local col (j=0,2): phase A; odd (j=1,3): phase B (pre-shifted one tap)
    h2_t wj[4][16];
    #pragma unroll
    for (int j = 0; j < 4; ++j) {
        const h2_t* wp = &wtab[idx[j] * WSTR + (j & 1) * 16];
        #pragma unroll
        for (int m = 0; m < 4; ++m) {
            h8_t v = *(const h8_t*)(wp + 4 * m);   // 16B aligned: WSTR%4==0
            #pragma unroll
            for (int q = 0; q < 4; ++q) {
                h2_t t2; t2.x = v[2 * q]; t2.y = v[2 * q + 1];
                wj[j][4 * m + q] = t2;
            }
        }
    }

// word I (h2) view of a folded h4 buffer F[9] -- pure register aliasing
#define RWW(F, I) mkh2(F[(I) >> 1][((I) & 1) * 2], F[(I) >> 1][((I) & 1) * 2 + 1])

// issue one row's 9 ds_read_b64 into an h4 buffer
#define ISSUE_ROW(DST, ROW)                                                  \
    {                                                                        \
        _Pragma("unroll")                                                    \
        for (int m = 0; m < 9; ++m)                                          \
            DST[m] = *(const h4_t*)(rowbase + (ROW) * TWORDS + 2 * m);       \
    }

#define ISSUE_PAIR(QA, QB, D)                                                \
    ISSUE_ROW(QA, 15 - (D))                                                  \
    ISSUE_ROW(QB, 15 + (D))

// in-place fold: QA[m] += QB[m]  (2x v_pk_add_f16 each; QA becomes the row)
#define FOLD(QA, QB)                                                         \
    {                                                                        \
        _Pragma("unroll")                                                    \
        for (int m = 0; m < 9; ++m) QA[m] = QA[m] + QB[m];                   \
    }

// horizontal dot on folded buffer F (words 0..16 used; rs2/3 shifted by 1)
#define HDOTF(F, RS0, RS1, RS2, RS3)                                         \
    {                                                                        \
        _Pragma("unroll")                                                    \
        for (int m = 0; m < 16; ++m) {                                       \
            RS0 = __builtin_amdgcn_fdot2(wj[0][m], RWW(F, m),     RS0, false);\
            RS1 = __builtin_amdgcn_fdot2(wj[1][m], RWW(F, m),     RS1, false);\
            RS2 = __builtin_amdgcn_fdot2(wj[2][m], RWW(F, m + 1), RS2, false);\
            RS3 = __builtin_amdgcn_fdot2(wj[3][m], RWW(F, m + 1), RS3, false);\
        }                                                                    \
    }

// column-weight extraction for compile-time DY (verified phase mapping)
#define CWEXT(DY, CW0, CW1, CW2, CW3)                                        \
    {                                                                        \
        if (((DY) & 1) == 0) {                                               \
            CW0 = (float)wj[0][(DY) >> 1].x;                                 \
            CW2 = (float)wj[2][(DY) >> 1].x;                                 \
            CW1 = (float)wj[1][(DY) >> 1].y;                                 \
            CW3 = (float)wj[3][(DY) >> 1].y;                                 \
        } else {                                                             \
            CW0 = (float)wj[0][(DY) >> 1].y;                                 \
            CW2 = (float)wj[2][(DY) >> 1].y;                                 \
            CW1 = (float)wj[1][((DY) + 1) >> 1].x;                           \
            CW3 = (float)wj[3][((DY) + 1) >> 1].x;                           \
        }                                                                    \
    }

// pipeline step for pair D: fold cur, issue pair D+1, hdot cur (no fences)
#define STEP(D, CQA, CQB, NQA, NQB, DOISSUE)                                 \
    {                                                                        \
        FOLD(CQA, CQB)                                                       \
        if (DOISSUE) { ISSUE_PAIR(NQA, NQB, (D) + 1) }                       \
        float rs0 = 0.f, rs1 = 0.f, rs2 = 0.f, rs3 = 0.f;                    \
        HDOTF(CQA, rs0, rs1, rs2, rs3)                                       \
        float cw0, cw1, cw2, cw3;                                            \
        CWEXT(15 - (D), cw0, cw1, cw2, cw3)                                  \
        acc0 += cw0 * rs0;  acc1 += cw1 * rs1;                               \
        acc2 += cw2 * rs2;  acc3 += cw3 * rs3;                               \
    }

    // ---- (6) per-channel: compute c (pipelined dy-loop), then stage c+1
    #pragma unroll 1
    for (int c = 0; c < CC; ++c) {
        float acc0 = 0.f, acc1 = 0.f, acc2 = 0.f, acc3 = 0.f;
        const h2_t* rowbase = &tile[ty * TWORDS + 2 * tx];

        h4_t Aqa[9], Aqb[9], Bqa[9], Bqb[9];

        // prologue: center row reads + pair-1 reads in flight
        ISSUE_ROW(Aqa, 15)
        ISSUE_PAIR(Bqa, Bqb, 1)

        // center row (dy = 15): no fold, waits only on Aqa's 9 reads
        {
            float rs0 = 0.f, rs1 = 0.f, rs2 = 0.f, rs3 = 0.f;
            HDOTF(Aqa, rs0, rs1, rs2, rs3)
            float cw0, cw1, cw2, cw3;
            CWEXT(15, cw0, cw1, cw2, cw3)
            acc0 += cw0 * rs0;  acc1 += cw1 * rs1;
            acc2 += cw2 * rs2;  acc3 += cw3 * rs3;
        }

        STEP(1,  Bqa, Bqb, Aqa, Aqb, 1)
        STEP(2,  Aqa, Aqb, Bqa, Bqb, 1)
        STEP(3,  Bqa, Bqb, Aqa, Aqb, 1)
        STEP(4,  Aqa, Aqb, Bqa, Bqb, 1)
        STEP(5,  Bqa, Bqb, Aqa, Aqb, 1)
        STEP(6,  Aqa, Aqb, Bqa, Bqb, 1)
        STEP(7,  Bqa, Bqb, Aqa, Aqb, 1)
        STEP(8,  Aqa, Aqb, Bqa, Bqb, 1)
        STEP(9,  Bqa, Bqb, Aqa, Aqb, 1)
        STEP(10, Aqa, Aqb, Bqa, Bqb, 1)
        STEP(11, Bqa, Bqb, Aqa, Aqb, 1)
        STEP(12, Aqa, Aqb, Bqa, Bqb, 1)
        STEP(13, Bqa, Bqb, Aqa, Aqb, 1)
        STEP(14, Aqa, Aqb, Bqa, Bqb, 1)
        STEP(15, Bqa, Bqb, Aqa, Aqb, 0)

        *(float4*)&out[((size_t)(b * CC + c) * HH + yo) * WW + xo] =
            make_float4(acc0, acc1, acc2, acc3);

        if (c + 1 < CC) {
            __syncthreads();   // this channel's readers done
            const float* src = img + (size_t)(b * CC + c + 1) * HH * WW;
            for (int f = tid; f < TILEW; f += NT) {
                int r = f / TWORDS;
                int w = f - r * TWORDS;
                int gy = tiley - 15 + r;
                int gx = tilex - 15 + 2 * w;
                float v0 = 0.f, v1 = 0.f;
                if ((unsigned)gy < (unsigned)HH) {
                    if ((unsigned)gx < (unsigned)WW) v0 = src[gy * WW + gx];
                    if ((unsigned)(gx + 1) < (unsigned)WW) v1 = src[gy * WW + gx + 1];
                }
                h2_t pv; pv.x = (_Float16)v0; pv.y = (_Float16)v1;
                tile[f] = pv;
            }
            __syncthreads();   // tile(c+1) ready
        }
    }

#undef RWW
#undef ISSUE_ROW
#undef ISSUE_PAIR
#undef FOLD
#undef HDOTF
#undef CWEXT
#undef STEP
}

extern "C" void kernel_launch(void* const* d_in, const int* in_sizes, int n_in,
                              void* d_out, int out_size, void* d_ws, size_t ws_size,
                              hipStream_t stream) {
    const float* sharp = (const float*)d_in[0];
    const float* cocm  = (const float*)d_in[1];
    float* out = (float*)d_out;

    dim3 grid(WW / TXO, HH / TYO, BB);   // 8 x 32 x 4 = 1024 blocks
    dim3 block(16, 16, 1);
    defocus_kernel<<<grid, block, 0, stream>>>(sharp, cocm, out);
}